// Round 14
// baseline (239.591 us; speedup 1.0000x reference)
//
#include <hip/hip_runtime.h>
#include <cstddef>

#define NPB  4096            // points per batch
#define KNB  20              // neighbors
#define NB   8               // batches
#define NPTS (NB * NPB)      // 32768 total points
#define NSEG 8               // segment-waves per block
#define SEGW 512             // candidates per segment
#define NSLOT 16             // push-buffer slots per thread
#define PCAP 32              // persistent pushed-list capacity per thread
#define MG   1e-3f           // fast-vs-exact dist margin (|err| <= ~1e-4)

// ---------------------------------------------------------------------------
// Kernel A+P (R15-validated): pack (x,y,z,xx) float4 + BN fold, w2f fold
// spread over 16 blocks with coalesced reads / scattered writes.
// ---------------------------------------------------------------------------
__global__ __launch_bounds__(256) void pack_prep_kernel(
    const float* __restrict__ x, float4* __restrict__ xp,
    const float* __restrict__ w1, const float* __restrict__ b1,
    const float* __restrict__ g1, const float* __restrict__ be1,
    const float* __restrict__ rm1, const float* __restrict__ rv1,
    const float* __restrict__ w2, const float* __restrict__ b2,
    const float* __restrict__ g2, const float* __restrict__ be2,
    const float* __restrict__ rm2, const float* __restrict__ rv2,
    float* __restrict__ w1f, float* __restrict__ w2f, float* __restrict__ w2b)
{
    const int tid = threadIdx.x;
    const int g = blockIdx.x * 256 + tid;
    const int b = g >> 12, n = g & (NPB - 1);
    const float* xb = x + (size_t)b * 3 * NPB;
    float a0 = xb[n], a1 = xb[NPB + n], a2 = xb[2 * NPB + n];
    float xx = __fadd_rn(__fadd_rn(__fmul_rn(a0, a0), __fmul_rn(a1, a1)),
                         __fmul_rn(a2, a2));
    xp[g] = make_float4(a0, a1, a2, xx);

    if (blockIdx.x == 0 && tid < 64) {
        float sc1 = g1[tid] * rsqrtf(rv1[tid] + 1e-5f);
        float sh1 = be1[tid] - rm1[tid] * sc1;
#pragma unroll
        for (int j = 0; j < 6; ++j) w1f[tid * 8 + j] = sc1 * w1[tid * 6 + j];
        w1f[tid * 8 + 6] = sc1 * b1[tid] + sh1;
        w1f[tid * 8 + 7] = 0.f;
        float sc2 = g2[tid] * rsqrtf(rv2[tid] + 1e-5f);
        w2b[tid] = sc2 * b2[tid] + (be2[tid] - rm2[tid] * sc2);
    }
    if (blockIdx.x < 16) {
#pragma unroll
        for (int r = 0; r < 2; ++r) {
            int j = blockIdx.x * 512 + r * 256 + tid;   // linear index into w2
            int o = j >> 7, c = j & 127;                // w2[o][c]
            float sc2 = g2[o] * rsqrtf(rv2[o] + 1e-5f);
            w2f[c * 64 + o] = sc2 * w2[j];
        }
    }
}

// ---------------------------------------------------------------------------
// Kernel B+C merged. R21 = R20 + pushed-list replay phase B:
//  - every survivor (d >= t) must have been PUSHED in the scan: dfast >=
//    dexact - 1e-4 > t - MG >= thrm at all times (thr <= t monotone).
//  - flush (which always gathers + computes exact d now) appends local idx
//    to a persistent per-thread list when d >= vals[19] (pre-insert).
//    Filter-safe: vals[19] monotone <= segment-20th-final <= t, so dropped
//    entries are d < t strictly; ties kept.
//  - phase B = replay: warm-up 0..19 streamed exact (never pushed) + list
//    walk (gather L1 + exact d >= t + append). Appends in scan order ->
//    dedup's ascending-index invariant preserved. Overflow (plc > PCAP):
//    whole wave falls back to the exact streamed scan (rare).
//  - scan pbuf is u16 idx-only (flush recomputes exact d; it gathers anyway).
// LDS re-packed: union max 72 KB, report stays 78848 -> 2 blocks/CU.
// ---------------------------------------------------------------------------
union KSMem {
    struct {                                // selection phase
        unsigned short plist[PCAP][512];    // 32 KB persistent pushed idx
        union {
            struct {
                unsigned short pbuf[NSLOT][512]; // 16 KB flush staging (idx)
                float4 shareV[NSEG][64];         //  8 KB {v20,v10,v5,v3}
            } s;                                 // 24 KB
            float vals[NSEG][KNB][64];           // 40 KB sorted lists
            struct {
                unsigned short list[NSEG][64][22]; // 22 KB survivors
                unsigned short cnt[NSEG][64];      //  1 KB
            } b;                                 // 23 KB
        } u;                                // 40 KB
    } sel;                                  // 72 KB
    struct {
        float cat[128 * 64];                // 32 KB [c][pt]
        float dif[KNB][3][64];              // 15 KB [k][coord][pt]
    } f;                                    // 47 KB   (union = 72 KB)
};

__global__ __launch_bounds__(512, 4) void knnfuse_kernel(
    const float4* __restrict__ xp,
    const float* __restrict__ w1f, const float* __restrict__ w2f,
    const float* __restrict__ w2b, float* __restrict__ out)
{
    __shared__ KSMem sm;
    __shared__ unsigned short outk[KNB][64];   // 2.5 KB final neighbor idx

    const int tid  = threadIdx.x;
    const int wv   = __builtin_amdgcn_readfirstlane(tid >> 6);
    const int lane = tid & 63;
    const int g0   = blockIdx.x * 64;
    const int b    = g0 >> 12;
    const int n0   = g0 & (NPB - 1);

    sm.sel.u.s.shareV[wv][lane] =
        make_float4(-INFINITY, -INFINITY, -INFINITY, -INFINITY);
    __syncthreads();

    const float4 me = xp[g0 + lane];                 // coalesced
    const float cx = me.x, cy = me.y, cz = me.z, xxn = me.w;
    const float cx2 = 2.0f * cx, cy2 = 2.0f * cy, cz2 = 2.0f * cz;
    const float nxx = -xxn;

    // exact reference-rounded dist (selection-critical path)
    auto dist = [&](float4 q) -> float {
        float inner = __fadd_rn(__fadd_rn(__fmul_rn(cx, q.x), __fmul_rn(cy, q.y)),
                                __fmul_rn(cz, q.z));
        return __fsub_rn(__fsub_rn(__fmul_rn(2.0f, inner), xxn), q.w);
    };
    // fast 4-op screen: |dfast - dist| <= ~1e-4 (values bounded ~200)
    auto dfast = [&](float4 q) -> float {
        return fmaf(cx2, q.x, fmaf(cy2, q.y, fmaf(cz2, q.z,
                    __fsub_rn(nxx, q.w))));
    };

    float vals[KNB];
#pragma unroll
    for (int j = 0; j < KNB; ++j) vals[j] = -INFINITY;

    const float4* cand = xp + (b << 12) + wv * SEGW; // wave-uniform -> s_load

    // warm-up: direct sorted insert of first 20 candidates, EXACT dist
    {
        float4 cw = cand[0];
#pragma unroll 1
        for (int i = 0; i < KNB; ++i) {
            float4 nxt = cand[i + 1];                // i+1 <= 20 < SEGW: safe
            float cv = dist(cw);
#pragma unroll
            for (int j = 0; j < KNB; ++j) {
                float nv = fmaxf(cv, vals[j]);
                cv       = fminf(cv, vals[j]);
                vals[j]  = nv;
            }
            cw = nxt;
        }
    }
    float vmin = vals[KNB - 1];
    float thr  = vmin;
    float thrm = thr - MG;                           // screened gate
    int   cnt  = 0;
    int   plc  = 0;                                  // persistent list count

    // (R16-J + R18) publish {v20,v10,v5,v3}; tighten thr with union bounds.
    auto refresh = [&]() {
        sm.sel.u.s.shareV[wv][lane] = make_float4(vmin, vals[9], vals[4], vals[2]);
        float4 s0 = sm.sel.u.s.shareV[0][lane], s1 = sm.sel.u.s.shareV[1][lane];
        float4 s2 = sm.sel.u.s.shareV[2][lane], s3 = sm.sel.u.s.shareV[3][lane];
        float4 s4 = sm.sel.u.s.shareV[4][lane], s5 = sm.sel.u.s.shareV[5][lane];
        float4 s6 = sm.sel.u.s.shareV[6][lane], s7 = sm.sel.u.s.shareV[7][lane];
        float m19 = fmaxf(fmaxf(fmaxf(s0.x, s1.x), fmaxf(s2.x, s3.x)),
                          fmaxf(fmaxf(s4.x, s5.x), fmaxf(s6.x, s7.x)));
        float b9 = fmaxf(fmaxf(fminf(s0.y, s1.y), fminf(s2.y, s3.y)),
                         fmaxf(fminf(s4.y, s5.y), fminf(s6.y, s7.y)));
        float q0 = fminf(fminf(s0.z, s1.z), fminf(s2.z, s3.z));
        float q1 = fminf(fminf(s4.z, s5.z), fminf(s6.z, s7.z));
        float b4 = fmaxf(q0, q1);
        float b3 = fminf(fminf(fminf(s0.w, s1.w), fminf(s2.w, s3.w)),
                         fminf(fminf(s4.w, s5.w), fminf(s6.w, s7.w)));
        thr = fmaxf(fmaxf(fmaxf(thr, m19), fmaxf(b9, b4)), b3);
        thrm = thr - MG;
    };
    refresh();                                       // early seed (lists full)

    // flush: gather cand[idx] (L1, 8 KB window), exact dist; record to
    // plist when d >= vals[19] (pre-insert); network-insert when useful.
    auto flush = [&]() {
        int ci = sm.sel.u.s.pbuf[0][tid];            // speculative 1-ahead
        float4 cq = cand[ci & (SEGW - 1)];
#pragma unroll
        for (int j = 0; j < NSLOT; ++j) {
            if (!__any(j < cnt)) break;
            int ni = (j + 1 < NSLOT) ? (int)sm.sel.u.s.pbuf[j + 1][tid] : 0;
            float4 nq = cand[ni & (SEGW - 1)];       // prefetch next gather
            float c = -INFINITY;
            if (j < cnt) {
                c = dist(cq);                        // exact 8-op
                if (c >= vals[KNB - 1]) {            // survivor-superset record
                    if (plc < PCAP) sm.sel.plist[plc][tid] = (unsigned short)ci;
                    ++plc;
                }
            }
            if (__any(c > vals[KNB - 1])) {          // stale-slot skip
#pragma unroll
                for (int q = 0; q < KNB; ++q) {      // 2-op step: max/min
                    float nv = fmaxf(c, vals[q]);
                    c        = fminf(c, vals[q]);
                    vals[q]  = nv;
                }
            }
            ci = ni; cq = nq;
        }
        vmin = vals[KNB - 1];
        cnt = 0;
        thr = fmaxf(thr, vmin);
        thrm = thr - MG;
    };

    // remainder of first 64-cand chunk, buffered (<=12 resident + 4 = 16)
    {
        float4 c4[4];
#pragma unroll
        for (int u = 0; u < 4; ++u) c4[u] = cand[KNB + u];
#pragma unroll 1
        for (int i = KNB; i < 64; i += 4) {
            float4 n4[4];
            const int nx = (i + 4 < 64) ? i + 4 : KNB;   // clamp: safe reload
#pragma unroll
            for (int u = 0; u < 4; ++u) n4[u] = cand[nx + u];
            if ((i & 15) == 4) refresh();            // i = 36, 52 (early flood)
#pragma unroll
            for (int u = 0; u < 4; ++u) {
                float d = dfast(c4[u]);
                if (d > thrm) {
                    sm.sel.u.s.pbuf[cnt][tid] = (unsigned short)(i + u);
                    ++cnt;
                }
            }
            if (__any(cnt >= 13)) flush();
#pragma unroll
            for (int u = 0; u < 4; ++u) c4[u] = n4[u];
        }
    }
    flush();                                         // leave cnt=0 for main

    // main scan: threshold refresh every 32, flush check every 8,
    // ping-pong 8-wide candidate prefetch across the backedge
    {
        float4 ca[8], cb[8];
#pragma unroll
        for (int u = 0; u < 8; ++u) ca[u] = cand[64 + u];
#pragma unroll 1
        for (int i = 64; i < SEGW; i += 16) {
#pragma unroll
            for (int u = 0; u < 8; ++u) cb[u] = cand[i + 8 + u];
            if ((i & 31) == 0) refresh();
#pragma unroll
            for (int u = 0; u < 8; ++u) {
                float d = dfast(ca[u]);
                if (d > thrm) {
                    sm.sel.u.s.pbuf[cnt][tid] = (unsigned short)(i + u);
                    ++cnt;
                }
            }
            if (__any(cnt >= 9)) flush();            // <=8 resident + 8 = 16
            const int nx = (i + 16 < SEGW) ? i + 16 : 64;  // clamp: safe
#pragma unroll
            for (int u = 0; u < 8; ++u) ca[u] = cand[nx + u];
#pragma unroll
            for (int u = 0; u < 8; ++u) {
                float d = dfast(cb[u]);
                if (d > thrm) {
                    sm.sel.u.s.pbuf[cnt][tid] = (unsigned short)(i + 8 + u);
                    ++cnt;
                }
            }
            if (__any(cnt >= 9)) flush();
        }
    }
    flush();
    __syncthreads();                                 // retire pbuf/shareV

#pragma unroll
    for (int j = 0; j < KNB; ++j) sm.sel.u.vals[wv][j][lane] = vals[j];
    __syncthreads();

    // every wave redundantly merges the 8 sorted value lists -> t (20th)
    float t = -INFINITY;
    {
        int p0 = 0, p1 = 0, p2 = 0, p3 = 0, p4 = 0, p5 = 0, p6 = 0, p7 = 0;
#pragma unroll 1
        for (int k = 0; k < KNB; ++k) {
            float e0 = sm.sel.u.vals[0][p0][lane], e1 = sm.sel.u.vals[1][p1][lane];
            float e2 = sm.sel.u.vals[2][p2][lane], e3 = sm.sel.u.vals[3][p3][lane];
            float e4 = sm.sel.u.vals[4][p4][lane], e5 = sm.sel.u.vals[5][p5][lane];
            float e6 = sm.sel.u.vals[6][p6][lane], e7 = sm.sel.u.vals[7][p7][lane];
            float bv = e0; int bs = 0;
            if (e1 > bv) { bv = e1; bs = 1; }
            if (e2 > bv) { bv = e2; bs = 2; }
            if (e3 > bv) { bv = e3; bs = 3; }
            if (e4 > bv) { bv = e4; bs = 4; }
            if (e5 > bv) { bv = e5; bs = 5; }
            if (e6 > bv) { bv = e6; bs = 6; }
            if (e7 > bv) { bv = e7; bs = 7; }
            t = bv;
            p0 += (bs == 0); p1 += (bs == 1); p2 += (bs == 2); p3 += (bs == 3);
            p4 += (bs == 4); p5 += (bs == 5); p6 += (bs == 6); p7 += (bs == 7);
        }
    }
    __syncthreads();                                 // retire vals (alias b)

    // phase B (R21): replay. Warm-up 0..19 streamed exact + plist walk.
    // Overflow wave: exact streamed fallback over all 512.
    int myc = 0;
    if (!__any(plc > PCAP)) {
        {   // warm-up replay: indices 0..19 (never pushed), ascending
            float4 cw = cand[0];
#pragma unroll 1
            for (int i = 0; i < KNB; ++i) {
                float4 nxt = cand[i + 1];
                float d = dist(cw);
                if (d >= t) {
                    if (myc < KNB)
                        sm.sel.u.b.list[wv][lane][myc] = (unsigned short)(
                            (wv * SEGW + i) | ((d > t) ? 0x8000 : 0));
                    ++myc;
                }
                cw = nxt;
            }
        }
        {   // plist walk (scan-order ascending), gather + exact dist
            int ci = sm.sel.plist[0][tid];
            float4 cq = cand[ci & (SEGW - 1)];
#pragma unroll 1
            for (int j = 0; j < PCAP; ++j) {
                if (!__any(j < plc)) break;
                int ni = (j + 1 < PCAP) ? (int)sm.sel.plist[j + 1][tid] : 0;
                float4 nq = cand[ni & (SEGW - 1)];
                if (j < plc) {
                    float d = dist(cq);
                    if (d >= t) {
                        if (myc < KNB)
                            sm.sel.u.b.list[wv][lane][myc] = (unsigned short)(
                                (wv * SEGW + ci) | ((d > t) ? 0x8000 : 0));
                        ++myc;
                    }
                }
                ci = ni; cq = nq;
            }
        }
    } else {
        // exact streamed fallback (rare): all 512, ping-pong prefetch
        float4 ca[8], cb[8];
#pragma unroll
        for (int u = 0; u < 8; ++u) ca[u] = cand[u];
#pragma unroll 1
        for (int i = 0; i < SEGW; i += 16) {
#pragma unroll
            for (int u = 0; u < 8; ++u) cb[u] = cand[i + 8 + u];
#pragma unroll
            for (int u = 0; u < 8; ++u) {
                float d = dist(ca[u]);
                if (d >= t) {
                    if (myc < KNB)
                        sm.sel.u.b.list[wv][lane][myc] = (unsigned short)(
                            (wv * SEGW + i + u) | ((d > t) ? 0x8000 : 0));
                    ++myc;
                }
            }
            const int nx = (i + 16 < SEGW) ? i + 16 : 0;
#pragma unroll
            for (int u = 0; u < 8; ++u) ca[u] = cand[nx + u];
#pragma unroll
            for (int u = 0; u < 8; ++u) {
                float d = dist(cb[u]);
                if (d >= t) {
                    if (myc < KNB)
                        sm.sel.u.b.list[wv][lane][myc] = (unsigned short)(
                            (wv * SEGW + i + 8 + u) | ((d > t) ? 0x8000 : 0));
                    ++myc;
                }
            }
        }
    }
    sm.sel.u.b.cnt[wv][lane] = (unsigned short)((myc < KNB) ? myc : KNB);
    __syncthreads();

    // dedup (wave 0): strict survivors first, then ties, ascending seg order
    if (wv == 0) {
        int nout = 0;
#pragma unroll 1
        for (int pass = 0; pass < 2; ++pass) {       // 0: d>t, 1: d==t
#pragma unroll 1
            for (int w = 0; w < NSEG; ++w) {
                int cw = sm.sel.u.b.cnt[w][lane];
#pragma unroll 1
                for (int j = 0; j < KNB; ++j) {
                    if (!__any(j < cw)) break;
                    if (j < cw) {
                        int e = sm.sel.u.b.list[w][lane][j];
                        bool strict = (e & 0x8000) != 0;
                        bool take = (pass == 0) ? strict : !strict;
                        if (take && nout < KNB) {
                            outk[nout][lane] = (unsigned short)(e & 0x0FFF);
                            ++nout;
                        }
                    }
                }
            }
        }
    }
    __syncthreads();                                 // outk ready; sel dead

    // ------------------- fused conv epilogue (R9-validated) -----------------
#pragma unroll
    for (int r = 0; r < 3; ++r) {
        int p = tid + r * 512;
        if (p < KNB * 64) {
            int k = p >> 6, pt = p & 63;
            int nb = outk[k][pt];
            float4 nq = xp[(b << 12) + nb];              // scattered (spread)
            float4 cq = xp[g0 + pt];                     // L1-hot
            sm.f.dif[k][0][pt] = __fsub_rn(nq.x, cq.x);
            sm.f.dif[k][1][pt] = __fsub_rn(nq.y, cq.y);
            sm.f.dif[k][2][pt] = __fsub_rn(nq.z, cq.z);
        }
    }
    __syncthreads();

    float dx[KNB], dy[KNB], dz[KNB];
#pragma unroll
    for (int k = 0; k < KNB; ++k) {                      // conflict-free LDS
        dx[k] = sm.f.dif[k][0][lane];
        dy[k] = sm.f.dif[k][1][lane];
        dz[k] = sm.f.dif[k][2][lane];
    }

    // conv1 eighth: channels [8*wv, 8*wv+8)
    const float4* w1fv = (const float4*)w1f;
#pragma unroll 1
    for (int cc = 0; cc < 8; ++cc) {
        int c = wv * 8 + cc;                             // uniform -> s_load
        float4 wa = w1fv[c * 2];                         // {W0,W1,W2,W3}
        float4 wb = w1fv[c * 2 + 1];                     // {W4,W5,B1',pad}
        float base = wb.z + wa.w * cx + wb.x * cy + wb.y * cz;
        float m1 = -INFINITY, s = 0.f;
#pragma unroll
        for (int k = 0; k < KNB; ++k) {
            float h = fmaf(dz[k], wa.z, fmaf(dy[k], wa.y, fmaf(dx[k], wa.x, base)));
            float r = fmaxf(0.f, h);
            m1 = fmaxf(m1, r);
            s += r;
        }
        sm.f.cat[c * 64 + lane]        = m1;
        sm.f.cat[(64 + c) * 64 + lane] = s / 20.0f;
    }
    __syncthreads();

    const size_t SEC = (size_t)NB * 64 * NPB;   // elements per output section

    // write m1/m2 rows straight from cat (coalesced 256B rows)
#pragma unroll 1
    for (int q = 0; q < 16; ++q) {
        int r  = wv * 16 + q;                   // 0..127, uniform
        int ch = r & 63;
        float* dst = out + SEC * (1 + (r >> 6)) + ((size_t)b * 64 + ch) * NPB + n0;
        dst[lane] = sm.f.cat[r * 64 + lane];
    }

    // conv2 eighth: outputs [8*wv, 8*wv+8)
    const int ob = wv * 8;                      // uniform -> s_load weights
    float acc[8];
#pragma unroll
    for (int j = 0; j < 8; ++j) acc[j] = w2b[ob + j];
#pragma unroll 4
    for (int c = 0; c < 128; ++c) {
        float v = sm.f.cat[c * 64 + lane];
        const float4* wr = (const float4*)(w2f + c * 64 + ob);
        float4 q0 = wr[0], q1 = wr[1];
        acc[0] = fmaf(v, q0.x, acc[0]);  acc[1] = fmaf(v, q0.y, acc[1]);
        acc[2] = fmaf(v, q0.z, acc[2]);  acc[3] = fmaf(v, q0.w, acc[3]);
        acc[4] = fmaf(v, q1.x, acc[4]);  acc[5] = fmaf(v, q1.y, acc[5]);
        acc[6] = fmaf(v, q1.z, acc[6]);  acc[7] = fmaf(v, q1.w, acc[7]);
    }
#pragma unroll
    for (int j = 0; j < 8; ++j) acc[j] = fmaxf(0.f, acc[j]);

    __syncthreads();                            // all waves done reading cat
#pragma unroll
    for (int j = 0; j < 8; ++j) sm.f.cat[(ob + j) * 64 + lane] = acc[j];
    __syncthreads();
#pragma unroll 1
    for (int q = 0; q < 8; ++q) {
        int oo = wv * 8 + q;
        out[((size_t)b * 64 + oo) * NPB + n0 + lane] = sm.f.cat[oo * 64 + lane];
    }
}

extern "C" void kernel_launch(void* const* d_in, const int* in_sizes, int n_in,
                              void* d_out, int out_size, void* d_ws, size_t ws_size,
                              hipStream_t stream) {
    const float* x   = (const float*)d_in[0];
    const float* w1  = (const float*)d_in[1];
    const float* b1  = (const float*)d_in[2];
    const float* g1  = (const float*)d_in[3];
    const float* be1 = (const float*)d_in[4];
    const float* rm1 = (const float*)d_in[5];
    const float* rv1 = (const float*)d_in[6];
    const float* w2  = (const float*)d_in[7];
    const float* b2  = (const float*)d_in[8];
    const float* g2  = (const float*)d_in[9];
    const float* be2 = (const float*)d_in[10];
    const float* rm2 = (const float*)d_in[11];
    const float* rv2 = (const float*)d_in[12];

    char*   ws  = (char*)d_ws;
    float4* xp  = (float4*)ws;                      // 512 KB
    float*  w1f = (float*)(ws + 512 * 1024);        // 2 KB
    float*  w2f = w1f + 64 * 8;                     // 32 KB
    float*  w2b = w2f + 64 * 128;                   // 256 B

    pack_prep_kernel<<<NPTS / 256, 256, 0, stream>>>(
        x, xp, w1, b1, g1, be1, rm1, rv1, w2, b2, g2, be2, rm2, rv2,
        w1f, w2f, w2b);
    knnfuse_kernel<<<NPTS / 64, 512, 0, stream>>>(xp, w1f, w2f, w2b,
                                                  (float*)d_out);
}

// Round 15
// 233.822 us; speedup vs baseline: 1.0247x; 1.0247x over previous
//
#include <hip/hip_runtime.h>
#include <cstddef>

#define NPB  4096            // points per batch
#define KNB  20              // neighbors
#define NB   8               // batches
#define NPTS (NB * NPB)      // 32768 total points
#define NSEG 8               // segment-waves per block
#define SEGW 512             // candidates per segment
#define NSLOT 16             // push-buffer slots per thread
#define MG   1e-3f           // fast-vs-exact dist margin (|err| <= ~1e-4)

// ---------------------------------------------------------------------------
// Kernel A+P (R15-validated): pack (x,y,z,xx) float4 + BN fold, w2f fold
// spread over 16 blocks with coalesced reads / scattered writes.
// ---------------------------------------------------------------------------
__global__ __launch_bounds__(256) void pack_prep_kernel(
    const float* __restrict__ x, float4* __restrict__ xp,
    const float* __restrict__ w1, const float* __restrict__ b1,
    const float* __restrict__ g1, const float* __restrict__ be1,
    const float* __restrict__ rm1, const float* __restrict__ rv1,
    const float* __restrict__ w2, const float* __restrict__ b2,
    const float* __restrict__ g2, const float* __restrict__ be2,
    const float* __restrict__ rm2, const float* __restrict__ rv2,
    float* __restrict__ w1f, float* __restrict__ w2f, float* __restrict__ w2b)
{
    const int tid = threadIdx.x;
    const int g = blockIdx.x * 256 + tid;
    const int b = g >> 12, n = g & (NPB - 1);
    const float* xb = x + (size_t)b * 3 * NPB;
    float a0 = xb[n], a1 = xb[NPB + n], a2 = xb[2 * NPB + n];
    float xx = __fadd_rn(__fadd_rn(__fmul_rn(a0, a0), __fmul_rn(a1, a1)),
                         __fmul_rn(a2, a2));
    xp[g] = make_float4(a0, a1, a2, xx);

    if (blockIdx.x == 0 && tid < 64) {
        float sc1 = g1[tid] * rsqrtf(rv1[tid] + 1e-5f);
        float sh1 = be1[tid] - rm1[tid] * sc1;
#pragma unroll
        for (int j = 0; j < 6; ++j) w1f[tid * 8 + j] = sc1 * w1[tid * 6 + j];
        w1f[tid * 8 + 6] = sc1 * b1[tid] + sh1;
        w1f[tid * 8 + 7] = 0.f;
        float sc2 = g2[tid] * rsqrtf(rv2[tid] + 1e-5f);
        w2b[tid] = sc2 * b2[tid] + (be2[tid] - rm2[tid] * sc2);
    }
    if (blockIdx.x < 16) {
#pragma unroll
        for (int r = 0; r < 2; ++r) {
            int j = blockIdx.x * 512 + r * 256 + tid;   // linear index into w2
            int o = j >> 7, c = j & 127;                // w2[o][c]
            float sc2 = g2[o] * rsqrtf(rv2[o] + 1e-5f);
            w2f[c * 64 + o] = sc2 * w2[j];
        }
    }
}

// ---------------------------------------------------------------------------
// Kernel B+C merged. R22 = R20 EXACT (measured best 162.6us; R21's
// pushed-list replay regressed to 172 — flush slot-passes are the dominant
// cost and R21 made each one heavier) + ONE change: main-scan thr refresh
// every 16 candidates (was 32). Halving the staleness window cuts
// over-pushes, directly reducing wave-max-paced flush slot-passes; refresh
// bounds are valid at any cadence (monotone-stale-safe).
// ---------------------------------------------------------------------------
union KSMem {
    int2 pbuf[NSLOT][512];          // 64 KB scan push pairs {dfast_bits, idx}
    float vals[NSEG][KNB][64];      // 40 KB sorted partial lists [wave][j][pt]
    struct {
        int list[NSEG][64][21];     // 42 KB survivors idx|(strict<<31)
        int cnt[NSEG][64];          //  2 KB
        unsigned short pb2[NSLOT][512];  // 16 KB phase-B push idx (local)
    } b;                            // 60 KB
    struct {
        float cat[128 * 64];        // 32 KB [c][pt]: c<64 m1, c>=64 m2
        float dif[KNB][3][64];      // 15 KB [k][coord][pt]
    } f;                            // 47 KB  (union = 64 KB)
};

__global__ __launch_bounds__(512, 4) void knnfuse_kernel(
    const float4* __restrict__ xp,
    const float* __restrict__ w1f, const float* __restrict__ w2f,
    const float* __restrict__ w2b, float* __restrict__ out)
{
    __shared__ KSMem sm;
    __shared__ float4 shareV[NSEG][64]; // 8 KB {v20, v10, v5, v3} per wave/pt
    __shared__ int   outk[KNB][64];     // 5 KB final neighbor idx [k][pt]

    const int tid  = threadIdx.x;
    const int wv   = __builtin_amdgcn_readfirstlane(tid >> 6);
    const int lane = tid & 63;
    const int g0   = blockIdx.x * 64;
    const int b    = g0 >> 12;
    const int n0   = g0 & (NPB - 1);

    shareV[wv][lane] = make_float4(-INFINITY, -INFINITY, -INFINITY, -INFINITY);
    __syncthreads();

    const float4 me = xp[g0 + lane];                 // coalesced
    const float cx = me.x, cy = me.y, cz = me.z, xxn = me.w;
    const float cx2 = 2.0f * cx, cy2 = 2.0f * cy, cz2 = 2.0f * cz;
    const float nxx = -xxn;

    // exact reference-rounded dist (selection-critical path)
    auto dist = [&](float4 q) -> float {
        float inner = __fadd_rn(__fadd_rn(__fmul_rn(cx, q.x), __fmul_rn(cy, q.y)),
                                __fmul_rn(cz, q.z));
        return __fsub_rn(__fsub_rn(__fmul_rn(2.0f, inner), xxn), q.w);
    };
    // fast 4-op screen: |dfast - dist| <= ~1e-4 (values bounded ~200)
    auto dfast = [&](float4 q) -> float {
        return fmaf(cx2, q.x, fmaf(cy2, q.y, fmaf(cz2, q.z,
                    __fsub_rn(nxx, q.w))));
    };

    float vals[KNB];
#pragma unroll
    for (int j = 0; j < KNB; ++j) vals[j] = -INFINITY;

    const float4* cand = xp + (b << 12) + wv * SEGW; // wave-uniform -> s_load

    // warm-up: direct sorted insert of first 20 candidates, EXACT dist
    {
        float4 cw = cand[0];
#pragma unroll 1
        for (int i = 0; i < KNB; ++i) {
            float4 nxt = cand[i + 1];                // i+1 <= 20 < SEGW: safe
            float cv = dist(cw);
#pragma unroll
            for (int j = 0; j < KNB; ++j) {
                float nv = fmaxf(cv, vals[j]);
                cv       = fminf(cv, vals[j]);
                vals[j]  = nv;
            }
            cw = nxt;
        }
    }
    float vmin = vals[KNB - 1];
    float thr  = vmin;
    float thrm = thr - MG;                           // screened gate
    int   cnt  = 0;

    // (R16-J + R18) publish {v20,v10,v5,v3}; tighten thr with union bounds.
    // racy by design: stale stats are older (smaller) -> still <= t.
    auto refresh = [&]() {
        shareV[wv][lane] = make_float4(vmin, vals[9], vals[4], vals[2]);
        float4 s0 = shareV[0][lane], s1 = shareV[1][lane];
        float4 s2 = shareV[2][lane], s3 = shareV[3][lane];
        float4 s4 = shareV[4][lane], s5 = shareV[5][lane];
        float4 s6 = shareV[6][lane], s7 = shareV[7][lane];
        float m19 = fmaxf(fmaxf(fmaxf(s0.x, s1.x), fmaxf(s2.x, s3.x)),
                          fmaxf(fmaxf(s4.x, s5.x), fmaxf(s6.x, s7.x)));
        float b9 = fmaxf(fmaxf(fminf(s0.y, s1.y), fminf(s2.y, s3.y)),
                         fmaxf(fminf(s4.y, s5.y), fminf(s6.y, s7.y)));
        float q0 = fminf(fminf(s0.z, s1.z), fminf(s2.z, s3.z));
        float q1 = fminf(fminf(s4.z, s5.z), fminf(s6.z, s7.z));
        float b4 = fmaxf(q0, q1);
        float b3 = fminf(fminf(fminf(s0.w, s1.w), fminf(s2.w, s3.w)),
                         fminf(fminf(s4.w, s5.w), fminf(s6.w, s7.w)));
        thr = fmaxf(fmaxf(fmaxf(thr, m19), fmaxf(b9, b4)), b3);
        thrm = thr - MG;
    };
    refresh();                                       // early seed (lists full)

    // flush: gather cand[idx] (L1, 8 KB window), insert EXACT dist.
    auto flush = [&]() {
        int2   cp = sm.pbuf[0][tid];                 // speculative 1-ahead
        float4 cq = cand[cp.y & (SEGW - 1)];         // sanitized spec gather
#pragma unroll
        for (int j = 0; j < NSLOT; ++j) {
            if (!__any(j < cnt)) break;
            int2 np = (j + 1 < NSLOT) ? sm.pbuf[j + 1][tid] : make_int2(0, 0);
            float4 nq = cand[np.y & (SEGW - 1)];     // prefetch next gather
            float cf = (j < cnt) ? __int_as_float(cp.x) : -INFINITY;
            if (__any(cf > vals[KNB - 1] - MG)) {    // (K) screened skip
                float c = (j < cnt) ? dist(cq) : -INFINITY;  // exact 8-op
#pragma unroll
                for (int q = 0; q < KNB; ++q) {      // 2-op step: max/min
                    float nv = fmaxf(c, vals[q]);
                    c        = fminf(c, vals[q]);
                    vals[q]  = nv;
                }
            }
            cp = np; cq = nq;
        }
        vmin = vals[KNB - 1];
        cnt = 0;
        thr = fmaxf(thr, vmin);
        thrm = thr - MG;
    };

    // remainder of first 64-cand chunk, buffered (<=12 resident + 4 = 16)
    {
        float4 c4[4];
#pragma unroll
        for (int u = 0; u < 4; ++u) c4[u] = cand[KNB + u];
#pragma unroll 1
        for (int i = KNB; i < 64; i += 4) {
            float4 n4[4];
            const int nx = (i + 4 < 64) ? i + 4 : KNB;   // clamp: safe reload
#pragma unroll
            for (int u = 0; u < 4; ++u) n4[u] = cand[nx + u];
            if ((i & 15) == 4) refresh();            // i = 36, 52 (early flood)
#pragma unroll
            for (int u = 0; u < 4; ++u) {
                float d = dfast(c4[u]);
                if (d > thrm) {
                    sm.pbuf[cnt][tid] = make_int2(__float_as_int(d), i + u);
                    ++cnt;
                }
            }
            if (__any(cnt >= 13)) flush();
#pragma unroll
            for (int u = 0; u < 4; ++u) c4[u] = n4[u];
        }
    }
    flush();                                         // leave cnt=0 for main

    // main scan: thr refresh every 16 (R22: was 32), flush check every 8,
    // ping-pong 8-wide candidate prefetch across the backedge
    {
        float4 ca[8], cb[8];
#pragma unroll
        for (int u = 0; u < 8; ++u) ca[u] = cand[64 + u];
#pragma unroll 1
        for (int i = 64; i < SEGW; i += 16) {
#pragma unroll
            for (int u = 0; u < 8; ++u) cb[u] = cand[i + 8 + u];
            refresh();                               // R22: every iteration
#pragma unroll
            for (int u = 0; u < 8; ++u) {
                float d = dfast(ca[u]);
                if (d > thrm) {
                    sm.pbuf[cnt][tid] = make_int2(__float_as_int(d), i + u);
                    ++cnt;
                }
            }
            if (__any(cnt >= 9)) flush();            // <=8 resident + 8 = 16
            const int nx = (i + 16 < SEGW) ? i + 16 : 64;  // clamp: safe
#pragma unroll
            for (int u = 0; u < 8; ++u) ca[u] = cand[nx + u];
#pragma unroll
            for (int u = 0; u < 8; ++u) {
                float d = dfast(cb[u]);
                if (d > thrm) {
                    sm.pbuf[cnt][tid] = make_int2(__float_as_int(d), i + 8 + u);
                    ++cnt;
                }
            }
            if (__any(cnt >= 9)) flush();
        }
    }
    flush();
    __syncthreads();                                 // retire push buffers

#pragma unroll
    for (int j = 0; j < KNB; ++j) sm.vals[wv][j][lane] = vals[j];
    __syncthreads();

    // every wave redundantly merges the 8 sorted value lists -> t (20th)
    float t = -INFINITY;
    {
        int p0 = 0, p1 = 0, p2 = 0, p3 = 0, p4 = 0, p5 = 0, p6 = 0, p7 = 0;
#pragma unroll 1
        for (int k = 0; k < KNB; ++k) {
            float e0 = sm.vals[0][p0][lane], e1 = sm.vals[1][p1][lane];
            float e2 = sm.vals[2][p2][lane], e3 = sm.vals[3][p3][lane];
            float e4 = sm.vals[4][p4][lane], e5 = sm.vals[5][p5][lane];
            float e6 = sm.vals[6][p6][lane], e7 = sm.vals[7][p7][lane];
            float bv = e0; int bs = 0;
            if (e1 > bv) { bv = e1; bs = 1; }
            if (e2 > bv) { bv = e2; bs = 2; }
            if (e3 > bv) { bv = e3; bs = 3; }
            if (e4 > bv) { bv = e4; bs = 4; }
            if (e5 > bv) { bv = e5; bs = 5; }
            if (e6 > bv) { bv = e6; bs = 6; }
            if (e7 > bv) { bv = e7; bs = 7; }
            t = bv;
            p0 += (bs == 0); p1 += (bs == 1); p2 += (bs == 2); p3 += (bs == 3);
            p4 += (bs == 4); p5 += (bs == 5); p6 += (bs == 6); p7 += (bs == 7);
        }
    }
    __syncthreads();                                 // retire vals (alias b)

    // phase B (R20): fast-screened streamed scan pushes u16 local idx of
    // dfast > t-MG passers (~2.5/thread); flush-style processing applies
    // EXACT dist for the d >= t filter + strict bit, appends in scan order.
    int myc = 0;
    {
        const float tm = t - MG;
        int cnt2 = 0;
        auto pbflush = [&]() {
            int ci = sm.b.pb2[0][tid];               // speculative 1-ahead
            float4 cq = cand[ci & (SEGW - 1)];
#pragma unroll
            for (int j = 0; j < NSLOT; ++j) {
                if (!__any(j < cnt2)) break;
                int ni = (j + 1 < NSLOT) ? (int)sm.b.pb2[j + 1][tid] : 0;
                float4 nq = cand[ni & (SEGW - 1)];
                if (j < cnt2) {
                    float d = dist(cq);              // exact 8-op
                    if (d >= t) {
                        if (myc < KNB)
                            sm.b.list[wv][lane][myc] =
                                (wv * SEGW + ci) | ((d > t) ? (int)0x80000000 : 0);
                        ++myc;
                    }
                }
                ci = ni; cq = nq;
            }
            cnt2 = 0;
        };
        float4 ca[8], cb[8];
#pragma unroll
        for (int u = 0; u < 8; ++u) ca[u] = cand[u];
#pragma unroll 1
        for (int i = 0; i < SEGW; i += 16) {
#pragma unroll
            for (int u = 0; u < 8; ++u) cb[u] = cand[i + 8 + u];
#pragma unroll
            for (int u = 0; u < 8; ++u) {
                float d = dfast(ca[u]);
                if (d > tm) { sm.b.pb2[cnt2][tid] = (unsigned short)(i + u); ++cnt2; }
            }
            if (__any(cnt2 >= 9)) pbflush();         // <=8 resident + 8 = 16
            const int nx = (i + 16 < SEGW) ? i + 16 : 0;   // clamp: safe
#pragma unroll
            for (int u = 0; u < 8; ++u) ca[u] = cand[nx + u];
#pragma unroll
            for (int u = 0; u < 8; ++u) {
                float d = dfast(cb[u]);
                if (d > tm) { sm.b.pb2[cnt2][tid] = (unsigned short)(i + 8 + u); ++cnt2; }
            }
            if (__any(cnt2 >= 9)) pbflush();
        }
        pbflush();
    }
    sm.b.cnt[wv][lane] = (myc < KNB) ? myc : KNB;
    __syncthreads();

    if (wv == 0) {
        int nout = 0;
#pragma unroll 1
        for (int pass = 0; pass < 2; ++pass) {       // 0: d>t, 1: d==t
#pragma unroll 1
            for (int w = 0; w < NSEG; ++w) {
                int cw = sm.b.cnt[w][lane];
#pragma unroll 1
                for (int j = 0; j < KNB; ++j) {
                    if (!__any(j < cw)) break;
                    if (j < cw) {
                        int e = sm.b.list[w][lane][j];
                        bool strict = (e < 0);
                        bool take = (pass == 0) ? strict : !strict;
                        if (take && nout < KNB) {
                            outk[nout][lane] = e & 0x7fffffff;
                            ++nout;
                        }
                    }
                }
            }
        }
    }
    __syncthreads();                                 // outk ready; b dead

    // ------------------- fused conv epilogue (R9-validated) -----------------
#pragma unroll
    for (int r = 0; r < 3; ++r) {
        int p = tid + r * 512;
        if (p < KNB * 64) {
            int k = p >> 6, pt = p & 63;
            int nb = outk[k][pt];
            float4 nq = xp[(b << 12) + nb];              // scattered (spread)
            float4 cq = xp[g0 + pt];                     // L1-hot
            sm.f.dif[k][0][pt] = __fsub_rn(nq.x, cq.x);
            sm.f.dif[k][1][pt] = __fsub_rn(nq.y, cq.y);
            sm.f.dif[k][2][pt] = __fsub_rn(nq.z, cq.z);
        }
    }
    __syncthreads();

    float dx[KNB], dy[KNB], dz[KNB];
#pragma unroll
    for (int k = 0; k < KNB; ++k) {                      // conflict-free LDS
        dx[k] = sm.f.dif[k][0][lane];
        dy[k] = sm.f.dif[k][1][lane];
        dz[k] = sm.f.dif[k][2][lane];
    }

    // conv1 eighth: channels [8*wv, 8*wv+8)
    const float4* w1fv = (const float4*)w1f;
#pragma unroll 1
    for (int cc = 0; cc < 8; ++cc) {
        int c = wv * 8 + cc;                             // uniform -> s_load
        float4 wa = w1fv[c * 2];                         // {W0,W1,W2,W3}
        float4 wb = w1fv[c * 2 + 1];                     // {W4,W5,B1',pad}
        float base = wb.z + wa.w * cx + wb.x * cy + wb.y * cz;
        float m1 = -INFINITY, s = 0.f;
#pragma unroll
        for (int k = 0; k < KNB; ++k) {
            float h = fmaf(dz[k], wa.z, fmaf(dy[k], wa.y, fmaf(dx[k], wa.x, base)));
            float r = fmaxf(0.f, h);
            m1 = fmaxf(m1, r);
            s += r;
        }
        sm.f.cat[c * 64 + lane]        = m1;
        sm.f.cat[(64 + c) * 64 + lane] = s / 20.0f;
    }
    __syncthreads();

    const size_t SEC = (size_t)NB * 64 * NPB;   // elements per output section

    // write m1/m2 rows straight from cat (coalesced 256B rows)
#pragma unroll 1
    for (int q = 0; q < 16; ++q) {
        int r  = wv * 16 + q;                   // 0..127, uniform
        int ch = r & 63;
        float* dst = out + SEC * (1 + (r >> 6)) + ((size_t)b * 64 + ch) * NPB + n0;
        dst[lane] = sm.f.cat[r * 64 + lane];
    }

    // conv2 eighth: outputs [8*wv, 8*wv+8)
    const int ob = wv * 8;                      // uniform -> s_load weights
    float acc[8];
#pragma unroll
    for (int j = 0; j < 8; ++j) acc[j] = w2b[ob + j];
#pragma unroll 4
    for (int c = 0; c < 128; ++c) {
        float v = sm.f.cat[c * 64 + lane];
        const float4* wr = (const float4*)(w2f + c * 64 + ob);
        float4 q0 = wr[0], q1 = wr[1];
        acc[0] = fmaf(v, q0.x, acc[0]);  acc[1] = fmaf(v, q0.y, acc[1]);
        acc[2] = fmaf(v, q0.z, acc[2]);  acc[3] = fmaf(v, q0.w, acc[3]);
        acc[4] = fmaf(v, q1.x, acc[4]);  acc[5] = fmaf(v, q1.y, acc[5]);
        acc[6] = fmaf(v, q1.z, acc[6]);  acc[7] = fmaf(v, q1.w, acc[7]);
    }
#pragma unroll
    for (int j = 0; j < 8; ++j) acc[j] = fmaxf(0.f, acc[j]);

    __syncthreads();                            // all waves done reading cat
#pragma unroll
    for (int j = 0; j < 8; ++j) sm.f.cat[(ob + j) * 64 + lane] = acc[j];
    __syncthreads();
#pragma unroll 1
    for (int q = 0; q < 8; ++q) {
        int oo = wv * 8 + q;
        out[((size_t)b * 64 + oo) * NPB + n0 + lane] = sm.f.cat[oo * 64 + lane];
    }
}

extern "C" void kernel_launch(void* const* d_in, const int* in_sizes, int n_in,
                              void* d_out, int out_size, void* d_ws, size_t ws_size,
                              hipStream_t stream) {
    const float* x   = (const float*)d_in[0];
    const float* w1  = (const float*)d_in[1];
    const float* b1  = (const float*)d_in[2];
    const float* g1  = (const float*)d_in[3];
    const float* be1 = (const float*)d_in[4];
    const float* rm1 = (const float*)d_in[5];
    const float* rv1 = (const float*)d_in[6];
    const float* w2  = (const float*)d_in[7];
    const float* b2  = (const float*)d_in[8];
    const float* g2  = (const float*)d_in[9];
    const float* be2 = (const float*)d_in[10];
    const float* rm2 = (const float*)d_in[11];
    const float* rv2 = (const float*)d_in[12];

    char*   ws  = (char*)d_ws;
    float4* xp  = (float4*)ws;                      // 512 KB
    float*  w1f = (float*)(ws + 512 * 1024);        // 2 KB
    float*  w2f = w1f + 64 * 8;                     // 32 KB
    float*  w2b = w2f + 64 * 128;                   // 256 B

    pack_prep_kernel<<<NPTS / 256, 256, 0, stream>>>(
        x, xp, w1, b1, g1, be1, rm1, rv1, w2, b2, g2, be2, rm2, rv2,
        w1f, w2f, w2b);
    knnfuse_kernel<<<NPTS / 64, 512, 0, stream>>>(xp, w1f, w2f, w2b,
                                                  (float*)d_out);
}

// Round 16
// 229.856 us; speedup vs baseline: 1.0424x; 1.0173x over previous
//
#include <hip/hip_runtime.h>
#include <cstddef>

#define NPB  4096            // points per batch
#define KNB  20              // neighbors
#define NB   8               // batches
#define NPTS (NB * NPB)      // 32768 total points
#define NSEG 8               // segment-waves per block
#define SEGW 512             // candidates per segment
#define NSLOT 16             // push-buffer slots per thread
#define MG   1e-3f           // fast-vs-exact dist margin (|err| <= ~1e-4)

// ---------------------------------------------------------------------------
// Kernel A+P (R15-validated): pack (x,y,z,xx) float4 + BN fold, w2f fold
// spread over 16 blocks with coalesced reads / scattered writes.
// ---------------------------------------------------------------------------
__global__ __launch_bounds__(256) void pack_prep_kernel(
    const float* __restrict__ x, float4* __restrict__ xp,
    const float* __restrict__ w1, const float* __restrict__ b1,
    const float* __restrict__ g1, const float* __restrict__ be1,
    const float* __restrict__ rm1, const float* __restrict__ rv1,
    const float* __restrict__ w2, const float* __restrict__ b2,
    const float* __restrict__ g2, const float* __restrict__ be2,
    const float* __restrict__ rm2, const float* __restrict__ rv2,
    float* __restrict__ w1f, float* __restrict__ w2f, float* __restrict__ w2b)
{
    const int tid = threadIdx.x;
    const int g = blockIdx.x * 256 + tid;
    const int b = g >> 12, n = g & (NPB - 1);
    const float* xb = x + (size_t)b * 3 * NPB;
    float a0 = xb[n], a1 = xb[NPB + n], a2 = xb[2 * NPB + n];
    float xx = __fadd_rn(__fadd_rn(__fmul_rn(a0, a0), __fmul_rn(a1, a1)),
                         __fmul_rn(a2, a2));
    xp[g] = make_float4(a0, a1, a2, xx);

    if (blockIdx.x == 0 && tid < 64) {
        float sc1 = g1[tid] * rsqrtf(rv1[tid] + 1e-5f);
        float sh1 = be1[tid] - rm1[tid] * sc1;
#pragma unroll
        for (int j = 0; j < 6; ++j) w1f[tid * 8 + j] = sc1 * w1[tid * 6 + j];
        w1f[tid * 8 + 6] = sc1 * b1[tid] + sh1;
        w1f[tid * 8 + 7] = 0.f;
        float sc2 = g2[tid] * rsqrtf(rv2[tid] + 1e-5f);
        w2b[tid] = sc2 * b2[tid] + (be2[tid] - rm2[tid] * sc2);
    }
    if (blockIdx.x < 16) {
#pragma unroll
        for (int r = 0; r < 2; ++r) {
            int j = blockIdx.x * 512 + r * 256 + tid;   // linear index into w2
            int o = j >> 7, c = j & 127;                // w2[o][c]
            float sc2 = g2[o] * rsqrtf(rv2[o] + 1e-5f);
            w2f[c * 64 + o] = sc2 * w2[j];
        }
    }
}

// ---------------------------------------------------------------------------
// Kernel B+C merged. R23 = R20 EXACT (measured best: 162.6us knnfuse /
// 228.4us total). Session plateau: VALU-work-bound, VALUBusy 77%.
// Validated levers: ping-pong prefetch (R11), threshold union-bounds +
// stale-slot skip (R16/R18), fast-screened scan with exact-at-flush (R19),
// fast-screened phase B (R20). Measured-worse alternatives: scattered
// bitmask phase B (R12), idx-carry network (R14), 16-wave blocks (R17,
// VGPR spill), pushed-list replay (R21), 2x refresh cadence (R22).
// ---------------------------------------------------------------------------
union KSMem {
    int2 pbuf[NSLOT][512];          // 64 KB scan push pairs {dfast_bits, idx}
    float vals[NSEG][KNB][64];      // 40 KB sorted partial lists [wave][j][pt]
    struct {
        int list[NSEG][64][21];     // 42 KB survivors idx|(strict<<31)
        int cnt[NSEG][64];          //  2 KB
        unsigned short pb2[NSLOT][512];  // 16 KB phase-B push idx (local)
    } b;                            // 60 KB
    struct {
        float cat[128 * 64];        // 32 KB [c][pt]: c<64 m1, c>=64 m2
        float dif[KNB][3][64];      // 15 KB [k][coord][pt]
    } f;                            // 47 KB  (union = 64 KB)
};

__global__ __launch_bounds__(512, 4) void knnfuse_kernel(
    const float4* __restrict__ xp,
    const float* __restrict__ w1f, const float* __restrict__ w2f,
    const float* __restrict__ w2b, float* __restrict__ out)
{
    __shared__ KSMem sm;
    __shared__ float4 shareV[NSEG][64]; // 8 KB {v20, v10, v5, v3} per wave/pt
    __shared__ int   outk[KNB][64];     // 5 KB final neighbor idx [k][pt]

    const int tid  = threadIdx.x;
    const int wv   = __builtin_amdgcn_readfirstlane(tid >> 6);
    const int lane = tid & 63;
    const int g0   = blockIdx.x * 64;
    const int b    = g0 >> 12;
    const int n0   = g0 & (NPB - 1);

    shareV[wv][lane] = make_float4(-INFINITY, -INFINITY, -INFINITY, -INFINITY);
    __syncthreads();

    const float4 me = xp[g0 + lane];                 // coalesced
    const float cx = me.x, cy = me.y, cz = me.z, xxn = me.w;
    const float cx2 = 2.0f * cx, cy2 = 2.0f * cy, cz2 = 2.0f * cz;
    const float nxx = -xxn;

    // exact reference-rounded dist (selection-critical path)
    auto dist = [&](float4 q) -> float {
        float inner = __fadd_rn(__fadd_rn(__fmul_rn(cx, q.x), __fmul_rn(cy, q.y)),
                                __fmul_rn(cz, q.z));
        return __fsub_rn(__fsub_rn(__fmul_rn(2.0f, inner), xxn), q.w);
    };
    // fast 4-op screen: |dfast - dist| <= ~1e-4 (values bounded ~200)
    auto dfast = [&](float4 q) -> float {
        return fmaf(cx2, q.x, fmaf(cy2, q.y, fmaf(cz2, q.z,
                    __fsub_rn(nxx, q.w))));
    };

    float vals[KNB];
#pragma unroll
    for (int j = 0; j < KNB; ++j) vals[j] = -INFINITY;

    const float4* cand = xp + (b << 12) + wv * SEGW; // wave-uniform -> s_load

    // warm-up: direct sorted insert of first 20 candidates, EXACT dist
    {
        float4 cw = cand[0];
#pragma unroll 1
        for (int i = 0; i < KNB; ++i) {
            float4 nxt = cand[i + 1];                // i+1 <= 20 < SEGW: safe
            float cv = dist(cw);
#pragma unroll
            for (int j = 0; j < KNB; ++j) {
                float nv = fmaxf(cv, vals[j]);
                cv       = fminf(cv, vals[j]);
                vals[j]  = nv;
            }
            cw = nxt;
        }
    }
    float vmin = vals[KNB - 1];
    float thr  = vmin;
    float thrm = thr - MG;                           // screened gate
    int   cnt  = 0;

    // (R16-J + R18) publish {v20,v10,v5,v3}; tighten thr with union bounds.
    // racy by design: stale stats are older (smaller) -> still <= t.
    auto refresh = [&]() {
        shareV[wv][lane] = make_float4(vmin, vals[9], vals[4], vals[2]);
        float4 s0 = shareV[0][lane], s1 = shareV[1][lane];
        float4 s2 = shareV[2][lane], s3 = shareV[3][lane];
        float4 s4 = shareV[4][lane], s5 = shareV[5][lane];
        float4 s6 = shareV[6][lane], s7 = shareV[7][lane];
        float m19 = fmaxf(fmaxf(fmaxf(s0.x, s1.x), fmaxf(s2.x, s3.x)),
                          fmaxf(fmaxf(s4.x, s5.x), fmaxf(s6.x, s7.x)));
        float b9 = fmaxf(fmaxf(fminf(s0.y, s1.y), fminf(s2.y, s3.y)),
                         fmaxf(fminf(s4.y, s5.y), fminf(s6.y, s7.y)));
        float q0 = fminf(fminf(s0.z, s1.z), fminf(s2.z, s3.z));
        float q1 = fminf(fminf(s4.z, s5.z), fminf(s6.z, s7.z));
        float b4 = fmaxf(q0, q1);
        float b3 = fminf(fminf(fminf(s0.w, s1.w), fminf(s2.w, s3.w)),
                         fminf(fminf(s4.w, s5.w), fminf(s6.w, s7.w)));
        thr = fmaxf(fmaxf(fmaxf(thr, m19), fmaxf(b9, b4)), b3);
        thrm = thr - MG;
    };
    refresh();                                       // early seed (lists full)

    // flush: gather cand[idx] (L1, 8 KB window), insert EXACT dist.
    auto flush = [&]() {
        int2   cp = sm.pbuf[0][tid];                 // speculative 1-ahead
        float4 cq = cand[cp.y & (SEGW - 1)];         // sanitized spec gather
#pragma unroll
        for (int j = 0; j < NSLOT; ++j) {
            if (!__any(j < cnt)) break;
            int2 np = (j + 1 < NSLOT) ? sm.pbuf[j + 1][tid] : make_int2(0, 0);
            float4 nq = cand[np.y & (SEGW - 1)];     // prefetch next gather
            float cf = (j < cnt) ? __int_as_float(cp.x) : -INFINITY;
            if (__any(cf > vals[KNB - 1] - MG)) {    // (K) screened skip
                float c = (j < cnt) ? dist(cq) : -INFINITY;  // exact 8-op
#pragma unroll
                for (int q = 0; q < KNB; ++q) {      // 2-op step: max/min
                    float nv = fmaxf(c, vals[q]);
                    c        = fminf(c, vals[q]);
                    vals[q]  = nv;
                }
            }
            cp = np; cq = nq;
        }
        vmin = vals[KNB - 1];
        cnt = 0;
        thr = fmaxf(thr, vmin);
        thrm = thr - MG;
    };

    // remainder of first 64-cand chunk, buffered (<=12 resident + 4 = 16)
    {
        float4 c4[4];
#pragma unroll
        for (int u = 0; u < 4; ++u) c4[u] = cand[KNB + u];
#pragma unroll 1
        for (int i = KNB; i < 64; i += 4) {
            float4 n4[4];
            const int nx = (i + 4 < 64) ? i + 4 : KNB;   // clamp: safe reload
#pragma unroll
            for (int u = 0; u < 4; ++u) n4[u] = cand[nx + u];
            if ((i & 15) == 4) refresh();            // i = 36, 52 (early flood)
#pragma unroll
            for (int u = 0; u < 4; ++u) {
                float d = dfast(c4[u]);
                if (d > thrm) {
                    sm.pbuf[cnt][tid] = make_int2(__float_as_int(d), i + u);
                    ++cnt;
                }
            }
            if (__any(cnt >= 13)) flush();
#pragma unroll
            for (int u = 0; u < 4; ++u) c4[u] = n4[u];
        }
    }
    flush();                                         // leave cnt=0 for main

    // main scan: threshold refresh every 32, flush check every 8,
    // ping-pong 8-wide candidate prefetch across the backedge
    {
        float4 ca[8], cb[8];
#pragma unroll
        for (int u = 0; u < 8; ++u) ca[u] = cand[64 + u];
#pragma unroll 1
        for (int i = 64; i < SEGW; i += 16) {
#pragma unroll
            for (int u = 0; u < 8; ++u) cb[u] = cand[i + 8 + u];
            if ((i & 31) == 0) refresh();
#pragma unroll
            for (int u = 0; u < 8; ++u) {
                float d = dfast(ca[u]);
                if (d > thrm) {
                    sm.pbuf[cnt][tid] = make_int2(__float_as_int(d), i + u);
                    ++cnt;
                }
            }
            if (__any(cnt >= 9)) flush();            // <=8 resident + 8 = 16
            const int nx = (i + 16 < SEGW) ? i + 16 : 64;  // clamp: safe
#pragma unroll
            for (int u = 0; u < 8; ++u) ca[u] = cand[nx + u];
#pragma unroll
            for (int u = 0; u < 8; ++u) {
                float d = dfast(cb[u]);
                if (d > thrm) {
                    sm.pbuf[cnt][tid] = make_int2(__float_as_int(d), i + 8 + u);
                    ++cnt;
                }
            }
            if (__any(cnt >= 9)) flush();
        }
    }
    flush();
    __syncthreads();                                 // retire push buffers

#pragma unroll
    for (int j = 0; j < KNB; ++j) sm.vals[wv][j][lane] = vals[j];
    __syncthreads();

    // every wave redundantly merges the 8 sorted value lists -> t (20th)
    float t = -INFINITY;
    {
        int p0 = 0, p1 = 0, p2 = 0, p3 = 0, p4 = 0, p5 = 0, p6 = 0, p7 = 0;
#pragma unroll 1
        for (int k = 0; k < KNB; ++k) {
            float e0 = sm.vals[0][p0][lane], e1 = sm.vals[1][p1][lane];
            float e2 = sm.vals[2][p2][lane], e3 = sm.vals[3][p3][lane];
            float e4 = sm.vals[4][p4][lane], e5 = sm.vals[5][p5][lane];
            float e6 = sm.vals[6][p6][lane], e7 = sm.vals[7][p7][lane];
            float bv = e0; int bs = 0;
            if (e1 > bv) { bv = e1; bs = 1; }
            if (e2 > bv) { bv = e2; bs = 2; }
            if (e3 > bv) { bv = e3; bs = 3; }
            if (e4 > bv) { bv = e4; bs = 4; }
            if (e5 > bv) { bv = e5; bs = 5; }
            if (e6 > bv) { bv = e6; bs = 6; }
            if (e7 > bv) { bv = e7; bs = 7; }
            t = bv;
            p0 += (bs == 0); p1 += (bs == 1); p2 += (bs == 2); p3 += (bs == 3);
            p4 += (bs == 4); p5 += (bs == 5); p6 += (bs == 6); p7 += (bs == 7);
        }
    }
    __syncthreads();                                 // retire vals (alias b)

    // phase B (R20): fast-screened streamed scan pushes u16 local idx of
    // dfast > t-MG passers (~2.5/thread); flush-style processing applies
    // EXACT dist for the d >= t filter + strict bit, appends in scan order.
    int myc = 0;
    {
        const float tm = t - MG;
        int cnt2 = 0;
        auto pbflush = [&]() {
            int ci = sm.b.pb2[0][tid];               // speculative 1-ahead
            float4 cq = cand[ci & (SEGW - 1)];
#pragma unroll
            for (int j = 0; j < NSLOT; ++j) {
                if (!__any(j < cnt2)) break;
                int ni = (j + 1 < NSLOT) ? (int)sm.b.pb2[j + 1][tid] : 0;
                float4 nq = cand[ni & (SEGW - 1)];
                if (j < cnt2) {
                    float d = dist(cq);              // exact 8-op
                    if (d >= t) {
                        if (myc < KNB)
                            sm.b.list[wv][lane][myc] =
                                (wv * SEGW + ci) | ((d > t) ? (int)0x80000000 : 0);
                        ++myc;
                    }
                }
                ci = ni; cq = nq;
            }
            cnt2 = 0;
        };
        float4 ca[8], cb[8];
#pragma unroll
        for (int u = 0; u < 8; ++u) ca[u] = cand[u];
#pragma unroll 1
        for (int i = 0; i < SEGW; i += 16) {
#pragma unroll
            for (int u = 0; u < 8; ++u) cb[u] = cand[i + 8 + u];
#pragma unroll
            for (int u = 0; u < 8; ++u) {
                float d = dfast(ca[u]);
                if (d > tm) { sm.b.pb2[cnt2][tid] = (unsigned short)(i + u); ++cnt2; }
            }
            if (__any(cnt2 >= 9)) pbflush();         // <=8 resident + 8 = 16
            const int nx = (i + 16 < SEGW) ? i + 16 : 0;   // clamp: safe
#pragma unroll
            for (int u = 0; u < 8; ++u) ca[u] = cand[nx + u];
#pragma unroll
            for (int u = 0; u < 8; ++u) {
                float d = dfast(cb[u]);
                if (d > tm) { sm.b.pb2[cnt2][tid] = (unsigned short)(i + 8 + u); ++cnt2; }
            }
            if (__any(cnt2 >= 9)) pbflush();
        }
        pbflush();
    }
    sm.b.cnt[wv][lane] = (myc < KNB) ? myc : KNB;
    __syncthreads();

    if (wv == 0) {
        int nout = 0;
#pragma unroll 1
        for (int pass = 0; pass < 2; ++pass) {       // 0: d>t, 1: d==t
#pragma unroll 1
            for (int w = 0; w < NSEG; ++w) {
                int cw = sm.b.cnt[w][lane];
#pragma unroll 1
                for (int j = 0; j < KNB; ++j) {
                    if (!__any(j < cw)) break;
                    if (j < cw) {
                        int e = sm.b.list[w][lane][j];
                        bool strict = (e < 0);
                        bool take = (pass == 0) ? strict : !strict;
                        if (take && nout < KNB) {
                            outk[nout][lane] = e & 0x7fffffff;
                            ++nout;
                        }
                    }
                }
            }
        }
    }
    __syncthreads();                                 // outk ready; b dead

    // ------------------- fused conv epilogue (R9-validated) -----------------
#pragma unroll
    for (int r = 0; r < 3; ++r) {
        int p = tid + r * 512;
        if (p < KNB * 64) {
            int k = p >> 6, pt = p & 63;
            int nb = outk[k][pt];
            float4 nq = xp[(b << 12) + nb];              // scattered (spread)
            float4 cq = xp[g0 + pt];                     // L1-hot
            sm.f.dif[k][0][pt] = __fsub_rn(nq.x, cq.x);
            sm.f.dif[k][1][pt] = __fsub_rn(nq.y, cq.y);
            sm.f.dif[k][2][pt] = __fsub_rn(nq.z, cq.z);
        }
    }
    __syncthreads();

    float dx[KNB], dy[KNB], dz[KNB];
#pragma unroll
    for (int k = 0; k < KNB; ++k) {                      // conflict-free LDS
        dx[k] = sm.f.dif[k][0][lane];
        dy[k] = sm.f.dif[k][1][lane];
        dz[k] = sm.f.dif[k][2][lane];
    }

    // conv1 eighth: channels [8*wv, 8*wv+8)
    const float4* w1fv = (const float4*)w1f;
#pragma unroll 1
    for (int cc = 0; cc < 8; ++cc) {
        int c = wv * 8 + cc;                             // uniform -> s_load
        float4 wa = w1fv[c * 2];                         // {W0,W1,W2,W3}
        float4 wb = w1fv[c * 2 + 1];                     // {W4,W5,B1',pad}
        float base = wb.z + wa.w * cx + wb.x * cy + wb.y * cz;
        float m1 = -INFINITY, s = 0.f;
#pragma unroll
        for (int k = 0; k < KNB; ++k) {
            float h = fmaf(dz[k], wa.z, fmaf(dy[k], wa.y, fmaf(dx[k], wa.x, base)));
            float r = fmaxf(0.f, h);
            m1 = fmaxf(m1, r);
            s += r;
        }
        sm.f.cat[c * 64 + lane]        = m1;
        sm.f.cat[(64 + c) * 64 + lane] = s / 20.0f;
    }
    __syncthreads();

    const size_t SEC = (size_t)NB * 64 * NPB;   // elements per output section

    // write m1/m2 rows straight from cat (coalesced 256B rows)
#pragma unroll 1
    for (int q = 0; q < 16; ++q) {
        int r  = wv * 16 + q;                   // 0..127, uniform
        int ch = r & 63;
        float* dst = out + SEC * (1 + (r >> 6)) + ((size_t)b * 64 + ch) * NPB + n0;
        dst[lane] = sm.f.cat[r * 64 + lane];
    }

    // conv2 eighth: outputs [8*wv, 8*wv+8)
    const int ob = wv * 8;                      // uniform -> s_load weights
    float acc[8];
#pragma unroll
    for (int j = 0; j < 8; ++j) acc[j] = w2b[ob + j];
#pragma unroll 4
    for (int c = 0; c < 128; ++c) {
        float v = sm.f.cat[c * 64 + lane];
        const float4* wr = (const float4*)(w2f + c * 64 + ob);
        float4 q0 = wr[0], q1 = wr[1];
        acc[0] = fmaf(v, q0.x, acc[0]);  acc[1] = fmaf(v, q0.y, acc[1]);
        acc[2] = fmaf(v, q0.z, acc[2]);  acc[3] = fmaf(v, q0.w, acc[3]);
        acc[4] = fmaf(v, q1.x, acc[4]);  acc[5] = fmaf(v, q1.y, acc[5]);
        acc[6] = fmaf(v, q1.z, acc[6]);  acc[7] = fmaf(v, q1.w, acc[7]);
    }
#pragma unroll
    for (int j = 0; j < 8; ++j) acc[j] = fmaxf(0.f, acc[j]);

    __syncthreads();                            // all waves done reading cat
#pragma unroll
    for (int j = 0; j < 8; ++j) sm.f.cat[(ob + j) * 64 + lane] = acc[j];
    __syncthreads();
#pragma unroll 1
    for (int q = 0; q < 8; ++q) {
        int oo = wv * 8 + q;
        out[((size_t)b * 64 + oo) * NPB + n0 + lane] = sm.f.cat[oo * 64 + lane];
    }
}

extern "C" void kernel_launch(void* const* d_in, const int* in_sizes, int n_in,
                              void* d_out, int out_size, void* d_ws, size_t ws_size,
                              hipStream_t stream) {
    const float* x   = (const float*)d_in[0];
    const float* w1  = (const float*)d_in[1];
    const float* b1  = (const float*)d_in[2];
    const float* g1  = (const float*)d_in[3];
    const float* be1 = (const float*)d_in[4];
    const float* rm1 = (const float*)d_in[5];
    const float* rv1 = (const float*)d_in[6];
    const float* w2  = (const float*)d_in[7];
    const float* b2  = (const float*)d_in[8];
    const float* g2  = (const float*)d_in[9];
    const float* be2 = (const float*)d_in[10];
    const float* rm2 = (const float*)d_in[11];
    const float* rv2 = (const float*)d_in[12];

    char*   ws  = (char*)d_ws;
    float4* xp  = (float4*)ws;                      // 512 KB
    float*  w1f = (float*)(ws + 512 * 1024);        // 2 KB
    float*  w2f = w1f + 64 * 8;                     // 32 KB
    float*  w2b = w2f + 64 * 128;                   // 256 B

    pack_prep_kernel<<<NPTS / 256, 256, 0, stream>>>(
        x, xp, w1, b1, g1, be1, rm1, rv1, w2, b2, g2, be2, rm2, rv2,
        w1f, w2f, w2b);
    knnfuse_kernel<<<NPTS / 64, 512, 0, stream>>>(xp, w1f, w2f, w2b,
                                                  (float*)d_out);
}